// Round 18
// baseline (249.881 us; speedup 1.0000x reference)
//
#include <hip/hip_runtime.h>
#include <math.h>

#define N_PIX 8192      // 2*64*64
#define D 64
#define HW 4096         // h*w
#define BSTRIDE 262144  // d*h*w
#define C1 14.4269504088896340736f   // 10 * log2(e)
#define LN2 0.6931471805599453f
#define NSEG 32
#define SEGCOLS 256
#define BC 256
#define NBLOCKS (32 * 32)

typedef __attribute__((ext_vector_type(8))) short short8;   // 8 bf16 = 4 VGPR
typedef __attribute__((ext_vector_type(4))) float f32x4;

#define LDS_AS __attribute__((address_space(3)))
#define GLB_AS __attribute__((address_space(1)))

__device__ inline ushort f2bf(float x) {   // fp32 -> bf16 RNE
    uint u = __float_as_uint(x);
    return (ushort)((u + 0x7FFFu + ((u >> 16) & 1u)) >> 16);
}

// async 16B global->LDS (dest = wave-uniform base + lane*16)
__device__ inline void gll16(const ushort* g, ushort* l) {
    __builtin_amdgcn_global_load_lds((const GLB_AS uint*)g, (LDS_AS uint*)l, 16, 0, 0);
}

// Stage BC cols x 64 ch bf16 into LDS, XOR-swizzled (verified r8-r17).
__device__ inline void stage(const ushort* __restrict__ z2b, int jcol,
                             ushort* ldsbuf, int wave, int lane) {
    int l3 = lane >> 3, l7 = lane & 7;
    int xo = (l7 ^ l3) << 3;     // ushort offset of swizzled 16B slot
#pragma unroll
    for (int q = 0; q < BC / 32; ++q) {
        int c = wave * (BC / 32) + q;
        const ushort* src = z2b + (size_t)(jcol + c * 8 + l3) * D + xo;
        gll16(src, ldsbuf + c * 512);
    }
}

// ---------- K1: transpose + L2-normalize -> bf16 rows; z1 pre-scaled by C1 ----------
__global__ __launch_bounds__(256) void knorm(const float* __restrict__ z1,
                                             const float* __restrict__ z2,
                                             ushort* __restrict__ z1b,
                                             ushort* __restrict__ z2b,
                                             float* __restrict__ rowsum,
                                             uint* __restrict__ ticket) {
    int gid = blockIdx.x * 256 + threadIdx.x;   // 0..65535
    if (gid < N_PIX) rowsum[gid] = 0.f;          // re-zero every call (atomic target)
    if (gid == 0) *ticket = 0;
    int q = gid & 3;                             // channel quarter
    int pixg = gid >> 2;                         // 0..16383
    int t = pixg >> 13;
    int n = pixg & (N_PIX - 1);
    const float* src = t ? z2 : z1;
    ushort* dst = t ? z2b : z1b;
    int b = n >> 12;
    int p = n & 4095;
    const float* base = src + b * BSTRIDE + (q * 16) * HW + p;
    float v[16];
    float ss = 0.f;
#pragma unroll
    for (int c = 0; c < 16; ++c) { v[c] = base[c * HW]; ss += v[c] * v[c]; }
    ss += __shfl_xor(ss, 1);                     // 4-lane group shares pixel
    ss += __shfl_xor(ss, 2);
    float inv = 1.0f / fmaxf(sqrtf(ss), 1e-12f);
    float sc = t ? inv : inv * C1;               // bake 10*log2(e) into z1 rows
    uint4 w0, w1;
#pragma unroll
    for (int c2 = 0; c2 < 8; ++c2) {
        uint val = (uint)f2bf(v[2 * c2] * sc) | ((uint)f2bf(v[2 * c2 + 1] * sc) << 16);
        if (c2 < 4) ((uint*)&w0)[c2] = val; else ((uint*)&w1)[c2 - 4] = val;
    }
    uint4* o = (uint4*)(dst + (size_t)n * D + q * 16);
    o[0] = w0;
    o[1] = w1;
}

// ---------- K2 (fused): MFMA sim + exp2 + atomic rowsum + diag + last-block final ----
// block = 4 waves x 64 rows = 256 rows x 256 cols; grid (32, 32) = 1024 blocks.
// acc = C1*dot (A pre-scaled); per-element cost: 1 exp2 + 1 add.
__global__ __launch_bounds__(256, 4) void ksim(const ushort* __restrict__ z1b,
                                               const ushort* __restrict__ z2b,
                                               float* __restrict__ rowsum,
                                               float* __restrict__ diag,
                                               uint* __restrict__ ticket,
                                               float* __restrict__ out) {
    __shared__ ushort lds[BC * D];   // 32KB
    __shared__ float redbuf[4];
    __shared__ uint lastFlag;
    int tid = threadIdx.x;
    int wave = tid >> 6, lane = tid & 63;
    int lrow = lane & 15;        // A-row / B-col within 16
    int lk = lane >> 4;          // k-chunk 0..3
    int bx = blockIdx.x, by = blockIdx.y;
    int rbase = bx * 256 + wave * 64;
    int jbase = by * SEGCOLS;

    stage(z2b, jbase, lds, wave, lane);          // 8 async 1KB chunks per wave

    // A fragments: 4 row-tiles x 2 k-halves
    const ushort* ar = z1b + (size_t)(rbase + lrow) * D + lk * 8;
    short8 a0[4], a1[4];
#pragma unroll
    for (int rt = 0; rt < 4; ++rt) {
        a0[rt] = *(const short8*)(ar + rt * 16 * D);
        a1[rt] = *(const short8*)(ar + rt * 16 * D + 32);
    }

    float s[16];
#pragma unroll
    for (int i = 0; i < 16; ++i) s[i] = 0.f;

    __syncthreads();                             // drain staging, once

    const char* bb = (const char*)lds;
    int sw = (lrow & 7);
    bool dblk = (bx == by);
    f32x4 z = {0.f, 0.f, 0.f, 0.f};

#pragma unroll
    for (int ct = 0; ct < BC / 16; ++ct) {
        int rowoff = (ct * 16 + lrow) << 7;
        short8 blo = *(const short8*)(bb + rowoff + ((lk ^ sw) << 4));
        short8 bhi = *(const short8*)(bb + rowoff + (((4 + lk) ^ sw) << 4));
#pragma unroll
        for (int rt = 0; rt < 4; ++rt) {
            f32x4 acc = __builtin_amdgcn_mfma_f32_16x16x32_bf16(a0[rt], blo, z, 0, 0, 0);
            acc = __builtin_amdgcn_mfma_f32_16x16x32_bf16(a1[rt], bhi, acc, 0, 0, 0);
            if (dblk && ct == wave * 4 + rt && (lrow >> 2) == lk) {   // diag = C1*dot
                int rr = lrow & 3;
                float dv = rr == 0 ? acc[0] : (rr == 1 ? acc[1] : (rr == 2 ? acc[2] : acc[3]));
                __hip_atomic_store(&diag[rbase + rt * 16 + lrow], dv,
                                   __ATOMIC_RELAXED, __HIP_MEMORY_SCOPE_AGENT);
            }
#pragma unroll
            for (int r = 0; r < 4; ++r)
                s[rt * 4 + r] += __builtin_amdgcn_exp2f(acc[r]);
        }
    }

    // reduce over 16 lanes sharing lk (different cols, same rows)
#pragma unroll
    for (int off = 1; off <= 8; off <<= 1) {
#pragma unroll
        for (int i = 0; i < 16; ++i) s[i] += __shfl_xor(s[i], off);
    }
    if (lrow == 0) {
#pragma unroll
        for (int rt = 0; rt < 4; ++rt)
#pragma unroll
            for (int r = 0; r < 4; ++r)
                atomicAdd(&rowsum[rbase + rt * 16 + lk * 4 + r], s[rt * 4 + r]);
    }

    // ---- last-block final: lse sum -> mean ----
    __threadfence();
    __syncthreads();
    if (tid == 0) lastFlag = (atomicAdd(ticket, 1u) == NBLOCKS - 1) ? 1u : 0u;
    __syncthreads();
    if (lastFlag) {
        float acc = 0.f;
        for (int r = tid; r < N_PIX; r += 256) {
            float sv = __hip_atomic_load(&rowsum[r], __ATOMIC_RELAXED, __HIP_MEMORY_SCOPE_AGENT);
            float dg = __hip_atomic_load(&diag[r], __ATOMIC_RELAXED, __HIP_MEMORY_SCOPE_AGENT);
            acc += __logf(sv) - LN2 * dg;        // ln(sum 2^acc) - 10*dot_rr
        }
#pragma unroll
        for (int off = 32; off > 0; off >>= 1) acc += __shfl_down(acc, off);
        if ((tid & 63) == 0) redbuf[tid >> 6] = acc;
        __syncthreads();
        if (tid == 0)
            out[0] = (redbuf[0] + redbuf[1] + redbuf[2] + redbuf[3]) * (1.0f / (float)N_PIX);
    }
}

extern "C" void kernel_launch(void* const* d_in, const int* in_sizes, int n_in,
                              void* d_out, int out_size, void* d_ws, size_t ws_size,
                              hipStream_t stream) {
    const float* z1 = (const float*)d_in[0];
    const float* z2 = (const float*)d_in[1];
    float* out = (float*)d_out;

    ushort* z1b   = (ushort*)d_ws;                      // 1 MB
    ushort* z2b   = z1b + (size_t)N_PIX * D;            // 1 MB
    float* rowsum = (float*)(z2b + (size_t)N_PIX * D);  // 32 KB
    float* diag   = rowsum + N_PIX;                     // 32 KB
    uint*  ticket = (uint*)(diag + N_PIX);              // 4 B

    knorm<<<256, 256, 0, stream>>>(z1, z2, z1b, z2b, rowsum, ticket);
    dim3 g2(N_PIX / 256, NSEG);                         // (32, 32) = 1024 blocks
    ksim<<<g2, 256, 0, stream>>>(z1b, z2b, rowsum, diag, ticket, out);
}

// Round 19
// 26.696 us; speedup vs baseline: 9.3603x; 9.3603x over previous
//
#include <hip/hip_runtime.h>
#include <math.h>

#define N_PIX 8192      // 2*64*64
#define D 64
#define HW 4096         // h*w
#define BSTRIDE 262144  // d*h*w
#define C1 14.4269504088896340736f   // 10 * log2(e)
#define LN2 0.6931471805599453f
#define NSEG 32
#define SEGCOLS 256
#define BC 256

typedef __attribute__((ext_vector_type(8))) short short8;   // 8 bf16 = 4 VGPR
typedef __attribute__((ext_vector_type(4))) float f32x4;

#define LDS_AS __attribute__((address_space(3)))
#define GLB_AS __attribute__((address_space(1)))

__device__ inline ushort f2bf(float x) {   // fp32 -> bf16 RNE
    uint u = __float_as_uint(x);
    return (ushort)((u + 0x7FFFu + ((u >> 16) & 1u)) >> 16);
}
__device__ inline float bflo(uint u) { return __uint_as_float(u << 16); }
__device__ inline float bfhi(uint u) { return __uint_as_float(u & 0xFFFF0000u); }

// async 16B global->LDS (dest = wave-uniform base + lane*16)
__device__ inline void gll16(const ushort* g, ushort* l) {
    __builtin_amdgcn_global_load_lds((const GLB_AS uint*)g, (LDS_AS uint*)l, 16, 0, 0);
}

// Stage BC cols x 64 ch bf16 into LDS, XOR-swizzled (verified r8-r17).
__device__ inline void stage(const ushort* __restrict__ z2b, int jcol,
                             ushort* ldsbuf, int wave, int lane) {
    int l3 = lane >> 3, l7 = lane & 7;
    int xo = (l7 ^ l3) << 3;     // ushort offset of swizzled 16B slot
#pragma unroll
    for (int q = 0; q < BC / 32; ++q) {
        int c = wave * (BC / 32) + q;
        const ushort* src = z2b + (size_t)(jcol + c * 8 + l3) * D + xo;
        gll16(src, ldsbuf + c * 512);
    }
}

// ---------- K1: transpose + L2-normalize; 8 threads/pixel; z1 pre-scaled by C1 ----------
// grid 512 x 256 = 131072 threads = 2048 waves (8 waves/CU TLP).
__global__ __launch_bounds__(256) void knorm(const float* __restrict__ z1,
                                             const float* __restrict__ z2,
                                             ushort* __restrict__ z1b,
                                             ushort* __restrict__ z2b,
                                             float* __restrict__ out) {
    int gid = blockIdx.x * 256 + threadIdx.x;   // 0..131071
    if (gid == 0) out[0] = 0.f;                 // fold memset (kfinal accumulates later)
    int q = gid & 7;                             // 8-channel group
    int pixg = gid >> 3;                         // 0..16383
    int t = pixg >> 13;
    int n = pixg & (N_PIX - 1);
    const float* src = t ? z2 : z1;
    ushort* dst = t ? z2b : z1b;
    int b = n >> 12;
    int p = n & 4095;
    const float* base = src + b * BSTRIDE + (q * 8) * HW + p;
    float v[8];
    float ss = 0.f;
#pragma unroll
    for (int c = 0; c < 8; ++c) { v[c] = base[(size_t)c * HW]; ss = fmaf(v[c], v[c], ss); }
    ss += __shfl_xor(ss, 1);                     // 8-lane group shares pixel
    ss += __shfl_xor(ss, 2);
    ss += __shfl_xor(ss, 4);
    float inv = 1.0f / fmaxf(sqrtf(ss), 1e-12f);
    float sc = t ? inv : inv * C1;               // bake 10*log2(e) into z1 rows
    uint4 w;
#pragma unroll
    for (int j = 0; j < 4; ++j) {
        ((uint*)&w)[j] = (uint)f2bf(v[2 * j] * sc) | ((uint)f2bf(v[2 * j + 1] * sc) << 16);
    }
    *(uint4*)(dst + (size_t)n * D + q * 8) = w;
}

// ---------- K2: MFMA sim + bare exp2; 64 rows/wave, zero mid barriers (r14 base) ----------
// block = 4 waves x 64 rows = 256 rows x 256 cols; grid (32, 32) = 1024 blocks = 4/CU.
// acc = C1*dot (z1 pre-scaled): per element just exp2 + add. No overflow (acc <= 14.43).
__global__ __launch_bounds__(256, 4) void ksim(const ushort* __restrict__ z1b,
                                               const ushort* __restrict__ z2b,
                                               float* __restrict__ ps) {
    __shared__ ushort lds[BC * D];   // 32KB
    int tid = threadIdx.x;
    int wave = tid >> 6, lane = tid & 63;
    int lrow = lane & 15;        // A-row / B-col within 16
    int lk = lane >> 4;          // k-chunk 0..3
    int rbase = blockIdx.x * 256 + wave * 64;
    int jbase = blockIdx.y * SEGCOLS;

    stage(z2b, jbase, lds, wave, lane);          // 8 async 1KB chunks per wave

    // A fragments: 4 row-tiles x 2 k-halves
    const ushort* ar = z1b + (size_t)(rbase + lrow) * D + lk * 8;
    short8 a0[4], a1[4];
#pragma unroll
    for (int rt = 0; rt < 4; ++rt) {
        a0[rt] = *(const short8*)(ar + rt * 16 * D);
        a1[rt] = *(const short8*)(ar + rt * 16 * D + 32);
    }

    float s[16];
#pragma unroll
    for (int i = 0; i < 16; ++i) s[i] = 0.f;

    __syncthreads();                             // drain staging, once

    const char* bb = (const char*)lds;
    int sw = (lrow & 7);
    f32x4 z = {0.f, 0.f, 0.f, 0.f};

#pragma unroll
    for (int ct = 0; ct < BC / 16; ++ct) {
        int rowoff = (ct * 16 + lrow) << 7;
        short8 blo = *(const short8*)(bb + rowoff + ((lk ^ sw) << 4));
        short8 bhi = *(const short8*)(bb + rowoff + (((4 + lk) ^ sw) << 4));
#pragma unroll
        for (int rt = 0; rt < 4; ++rt) {
            f32x4 acc = __builtin_amdgcn_mfma_f32_16x16x32_bf16(a0[rt], blo, z, 0, 0, 0);
            acc = __builtin_amdgcn_mfma_f32_16x16x32_bf16(a1[rt], bhi, acc, 0, 0, 0);
#pragma unroll
            for (int r = 0; r < 4; ++r)
                s[rt * 4 + r] += __builtin_amdgcn_exp2f(acc[r]);
        }
    }

    // reduce over 16 lanes sharing lk (different cols, same rows)
#pragma unroll
    for (int off = 1; off <= 8; off <<= 1) {
#pragma unroll
        for (int i = 0; i < 16; ++i) s[i] += __shfl_xor(s[i], off);
    }
    if (lrow == 0) {
        int seg = blockIdx.y;
#pragma unroll
        for (int rt = 0; rt < 4; ++rt)
#pragma unroll
            for (int r = 0; r < 4; ++r)
                ps[(size_t)(rbase + rt * 16 + lk * 4 + r) * NSEG + seg] = s[rt * 4 + r];
    }
}

// ---------- K3: combine partials + diag + mean via atomic ----------
// d = C1*dot (z1b pre-scaled); val = ln(sum 2^acc) - ln2*d.
__global__ __launch_bounds__(64) void kfinal(const ushort* __restrict__ z1b,
                                             const ushort* __restrict__ z2b,
                                             const float* __restrict__ ps,
                                             float* __restrict__ out) {
    int tid = threadIdx.x;
    int row = blockIdx.x * 64 + tid;

    const f32x4* pp = (const f32x4*)(ps + (size_t)row * NSEG);
    float s = 0.f;
#pragma unroll
    for (int q = 0; q < NSEG / 4; ++q) {
        f32x4 v = pp[q];
        s += (v[0] + v[1]) + (v[2] + v[3]);
    }
    const uint4* xp = (const uint4*)(z1b + (size_t)row * D);
    const uint4* yp = (const uint4*)(z2b + (size_t)row * D);
    float d = 0.f;
#pragma unroll
    for (int q = 0; q < 8; ++q) {
        uint4 x = xp[q], y = yp[q];
        d = fmaf(bflo(x.x), bflo(y.x), d); d = fmaf(bfhi(x.x), bfhi(y.x), d);
        d = fmaf(bflo(x.y), bflo(y.y), d); d = fmaf(bfhi(x.y), bfhi(y.y), d);
        d = fmaf(bflo(x.z), bflo(y.z), d); d = fmaf(bfhi(x.z), bfhi(y.z), d);
        d = fmaf(bflo(x.w), bflo(y.w), d); d = fmaf(bfhi(x.w), bfhi(y.w), d);
    }
    float val = __logf(s) - LN2 * d;

#pragma unroll
    for (int off = 32; off > 0; off >>= 1) val += __shfl_down(val, off);
    if (tid == 0) atomicAdd(out, val * (1.0f / (float)N_PIX));
}

extern "C" void kernel_launch(void* const* d_in, const int* in_sizes, int n_in,
                              void* d_out, int out_size, void* d_ws, size_t ws_size,
                              hipStream_t stream) {
    const float* z1 = (const float*)d_in[0];
    const float* z2 = (const float*)d_in[1];
    float* out = (float*)d_out;

    ushort* z1b = (ushort*)d_ws;                        // 1 MB
    ushort* z2b = z1b + (size_t)N_PIX * D;              // 1 MB
    float* ps   = (float*)(z2b + (size_t)N_PIX * D);    // 8192*32*4 = 1 MB

    knorm<<<512, 256, 0, stream>>>(z1, z2, z1b, z2b, out);
    dim3 g2(N_PIX / 256, NSEG);                         // (32, 32) = 1024 blocks
    ksim<<<g2, 256, 0, stream>>>(z1b, z2b, ps);
    kfinal<<<N_PIX / 64, 64, 0, stream>>>(z1b, z2b, ps, out);
}